// Round 13
// baseline (194.455 us; speedup 1.0000x reference)
//
#include <hip/hip_runtime.h>
#include <hip/hip_bf16.h>

#define Bsz 8
#define Tsz 16384
#define NL0 16385
#define NL5 512

typedef __attribute__((ext_vector_type(2))) float f32x2;
typedef __attribute__((ext_vector_type(4))) float f32x4;
typedef __attribute__((ext_vector_type(8))) short bf16x8;

__device__ __forceinline__ short f2bf(float f) {
  unsigned u = __builtin_bit_cast(unsigned, f);
  u += 0x7FFFu + ((u >> 16) & 1u);
  return (short)(u >> 16);
}
__device__ __forceinline__ unsigned cvtpk(float lo, float hi) {
  __hip_bfloat162 t = __float22bfloat162_rn(float2{lo, hi});
  unsigned u;
  __builtin_memcpy(&u, &t, 4);
  return u;
}
__device__ __forceinline__ bf16x8 pack8(f32x4 a, f32x4 b) {
  union { unsigned u[4]; bf16x8 v; } r;
  r.u[0] = cvtpk(a[0], a[1]); r.u[1] = cvtpk(a[2], a[3]);
  r.u[2] = cvtpk(b[0], b[1]); r.u[3] = cvtpk(b[2], b[3]);
  return r.v;
}
__device__ __forceinline__ void unpk(unsigned u, float& a, float& b) {
  a = __builtin_bit_cast(float, u << 16);
  b = __builtin_bit_cast(float, u & 0xFFFF0000u);
}

// ---------------------------------------------------------------- sentinel
__global__ void fill_sentinel(float* __restrict__ out, int n) {
  int i = blockIdx.x * blockDim.x + threadIdx.x;
  if (i < n) out[i] = 12345.0f;
}

// ---------------------------------------------------------------- weight prep: fp32 [256][256] -> bf16 tiled [c/8][r][c%8]
__global__ void prep_weights(const float* __restrict__ Wz, const float* __restrict__ Wh,
                             const float* __restrict__ Wo, unsigned short* __restrict__ wt) {
  int idx = blockIdx.x * 256 + threadIdx.x;          // 3 * 256 * 32
  if (idx >= 3 * 256 * 32) return;
  int m   = idx >> 13;
  int rem = idx & 8191;
  int r   = rem >> 5;
  int cq  = rem & 31;
  const float* src = (m == 0 ? Wz : (m == 1 ? Wh : Wo)) + r * 256 + cq * 8;
  f32x4 v0 = *(const f32x4*)src;
  f32x4 v1 = *(const f32x4*)(src + 4);
  *(bf16x8*)(wt + m * 65536 + (cq * 256 + r) * 8) = pack8(v0, v1);
}

// ---------------------------------------------------------------- GEMM 1 + fused chunk up-sweep (32-bit addressing)
// Block cb computes L0 indices [32cb, 32cb+32), all 256 h; in-wave 5-level reduce
// on bf16-ROUNDED (a,b) -> l5. cb==512 tail writes only idx 16384.
__global__ __launch_bounds__(256, 3)
void gemm_zh(const float* __restrict__ xs, const unsigned short* __restrict__ wt,
             const float* __restrict__ bz, const float* __restrict__ bh,
             unsigned* __restrict__ l0, f32x2* __restrict__ l5)
{
  __shared__ __align__(16) unsigned short aL[32][32][8];  // [row][oct^(row&7)][8] = 16 KB

  const int tid = threadIdx.x;
  const int wave = tid >> 6, lane = tid & 63, l15 = lane & 15, l4 = lane >> 4;
  const int bid = blockIdx.x;
  const int batch = bid / 513;
  const int cb = bid - batch * 513;
  const unsigned short* wz_t = wt;
  const unsigned short* wh_t = wt + 65536;
  const int wn = wave * 64;

  // per-batch base pointers (computed once; all in-kernel offsets are 32-bit)
  unsigned* const l0b = l0 + (size_t)batch * (NL0 * 256);
  f32x2* const l5b = l5 + (size_t)batch * (512 * 256);

  {
    const int gr0i = batch * Tsz + 32 * cb - 1;          // xs row of LDS row 0
    const int rowsMax = Bsz * Tsz - 1;
    f32x4 av0[4], av1[4];
#pragma unroll
    for (int k = 0; k < 4; ++k) {
      const int row = (tid >> 5) + k * 8;
      const int col = (tid & 31) * 8;
      int gr = gr0i + row;
      gr = gr < 0 ? 0 : (gr > rowsMax ? rowsMax : gr);
      const float* p = xs + (((unsigned)gr << 8) + (unsigned)col);
      av0[k] = *(const f32x4*)p;
      av1[k] = *(const f32x4*)(p + 4);
    }
#pragma unroll
    for (int k = 0; k < 4; ++k) {
      const int o = tid + k * 256;          // flat octet = row*32 + oct
      const int row = o >> 5, oct = o & 31;
      *(bf16x8*)&aL[row][oct ^ (row & 7)][0] = pack8(av0[k], av1[k]);
    }
  }
  __syncthreads();

  f32x4 accz[2][4] = {};
  f32x4 acch[2][4] = {};

#pragma unroll
  for (int kk = 0; kk < 8; ++kk) {                       // K=32 per step
    bf16x8 af[2];
#pragma unroll
    for (int m = 0; m < 2; ++m) {
      const int row = m * 16 + l15;
      af[m] = *(const bf16x8*)&aL[row][(kk * 4 + l4) ^ (row & 7)][0];
    }
    const int cq = kk * 4 + l4;
    bf16x8 zf[4], hf[4];
#pragma unroll
    for (int n = 0; n < 4; ++n) {
      const int r = wn + n * 16 + l15;
      zf[n] = *(const bf16x8*)(wz_t + (cq * 256 + r) * 8);
      hf[n] = *(const bf16x8*)(wh_t + (cq * 256 + r) * 8);
    }
#pragma unroll
    for (int m = 0; m < 2; ++m)
#pragma unroll
      for (int n = 0; n < 4; ++n) {
        accz[m][n] = __builtin_amdgcn_mfma_f32_16x16x32_bf16(af[m], zf[n], accz[m][n], 0, 0, 0);
        acch[m][n] = __builtin_amdgcn_mfma_f32_16x16x32_bf16(af[m], hf[n], acch[m][n], 0, 0, 0);
      }
  }

  // ---- epilogue: (a,b), identity override, l0 write (32-bit offsets), reduce
  const unsigned base0 = ((unsigned)(32 * cb) << 8) + (unsigned)(wn + l15) + ((unsigned)l4 << 10);
#pragma unroll
  for (int n = 0; n < 4; ++n) {
    const int col = wn + n * 16 + l15;
    const float bzv = bz[col], bhv = bh[col];
#pragma unroll
    for (int m = 0; m < 2; ++m)
#pragma unroll
      for (int j = 0; j < 4; ++j) {
        const int e = m * 16 + l4 * 4 + j;               // slot within chunk
        const float zv = 1.0f / (1.0f + __expf(-(accz[m][n][j] + bzv)));
        const float hv = acch[m][n][j] + bhv;
        float a = 1.0f - zv, b = zv * hv;
        if (cb == 0 && e == 0) { a = 1.0f; b = 0.0f; }   // prepended identity
        const unsigned u = cvtpk(a, b);
        if (cb < 512 || e == 0)
          l0b[base0 + (unsigned)(n * 16 + m * 4096 + j * 256)] = u;
        // keep ROUNDED values for the reduce (bit-identical to old path)
        float ar, br; unpk(u, ar, br);
        accz[m][n][j] = ar; acch[m][n][j] = br;
      }
  }

  if (cb < 512) {
    const bool f3 = (l4 & 1) == 0;
    const bool f4 = (l4 & 2) == 0;
#pragma unroll
    for (int n = 0; n < 4; ++n) {
      float a4v[2], b4v[2];
#pragma unroll
      for (int m = 0; m < 2; ++m) {
        const float a10 = accz[m][n][0] * acch[m][n][0];
        const float b10 = acch[m][n][0] * accz[m][n][1] + acch[m][n][1];
        const float a11 = accz[m][n][2] * acch[m][n][2];
        const float b11 = acch[m][n][2] * accz[m][n][3] + acch[m][n][3];
        const float a2 = a10 * b10;
        const float b2 = b10 * a11 + b11;
        const float pa = __shfl_xor(a2, 16);
        const float pb = __shfl_xor(b2, 16);
        const float a3 = f3 ? a2 * b2 : pa * pb;
        const float b3 = f3 ? b2 * pa + pb : pb * a2 + b2;
        const float qa = __shfl_xor(a3, 32);
        const float qb = __shfl_xor(b3, 32);
        a4v[m] = f4 ? a3 * b3 : qa * qb;
        b4v[m] = f4 ? b3 * qa + qb : qb * a3 + b3;
      }
      const float a5 = a4v[0] * b4v[0];
      const float b5 = b4v[0] * a4v[1] + b4v[1];
      if (l4 == 0)
        l5b[((unsigned)cb << 8) + (unsigned)(wn + n * 16 + l15)] = f32x2{a5, b5};
    }
  }
}

// ---------------------------------------------------------------- fused mid-level scan: L5 -> s5b (one kernel, 8 blocks)
// pass 1: up-sweep L5 (512) -> L10 (16) in regs; tree16 scan in regs;
// pass 2: re-read L5 per chunk (L2-resident), emit s5b. Bodies identical to
// the former chunk_up / tree16 / chunk_down_f32 kernels (bit-identical).
__global__ __launch_bounds__(256)
void mid_scan(const f32x2* __restrict__ l5, float* __restrict__ s5b)
{
  const int batch = blockIdx.x;
  const int h = threadIdx.x;
  const f32x2* src = l5 + (size_t)batch * (512 * 256) + h;
  float* dst = s5b + (size_t)batch * (512 * 256) + h;

  // pass 1: 16 chunks of 32 -> la/lb (L10)
  float la[16], lb[16];
#pragma unroll 1
  for (int c = 0; c < 16; ++c) {
    float a1[16], b1[16];
#pragma unroll
    for (int i = 0; i < 16; ++i) {
      f32x2 e0 = src[(unsigned)(c * 32 + 2 * i) << 8];
      f32x2 e1 = src[(unsigned)(c * 32 + 2 * i + 1) << 8];
      a1[i] = e0[0] * e0[1];
      b1[i] = e0[1] * e1[0] + e1[1];
    }
#pragma unroll
    for (int n = 8; n >= 1; n >>= 1)
#pragma unroll
      for (int i = 0; i < n; ++i) {
        float na = a1[2 * i] * b1[2 * i];
        float nb = b1[2 * i] * a1[2 * i + 1] + b1[2 * i + 1];
        a1[i] = na; b1[i] = nb;
      }
    la[c] = a1[0]; lb[c] = b1[0];
  }

  // tree16 (exact JAX odd-even scan of the 16 L10 elements)
  float s10[16];
  {
    float a1[8], b1[8];
#pragma unroll
    for (int i = 0; i < 8; ++i) { a1[i] = la[2*i]*lb[2*i]; b1[i] = lb[2*i]*la[2*i+1] + lb[2*i+1]; }
    float a2[4], b2[4];
#pragma unroll
    for (int i = 0; i < 4; ++i) { a2[i] = a1[2*i]*b1[2*i]; b2[i] = b1[2*i]*a1[2*i+1] + b1[2*i+1]; }
    float a3[2], b3[2];
#pragma unroll
    for (int i = 0; i < 2; ++i) { a3[i] = a2[2*i]*b2[2*i]; b3[i] = b2[2*i]*a2[2*i+1] + b2[2*i+1]; }
    float s3[2];
    s3[0] = b3[0];
    s3[1] = b3[0] * a3[1] + b3[1];
    float s2[4];
    s2[0] = b2[0]; s2[1] = s3[0]; s2[2] = s3[0] * a2[2] + b2[2]; s2[3] = s3[1];
    float s1[8];
    s1[0] = b1[0];
#pragma unroll
    for (int j = 0; j < 4; ++j) s1[2*j+1] = s2[j];
#pragma unroll
    for (int j = 1; j < 4; ++j) s1[2*j] = s2[j-1] * a1[2*j] + b1[2*j];
    s10[0] = lb[0];
#pragma unroll
    for (int j = 0; j < 8; ++j) s10[2*j+1] = s1[j];
#pragma unroll
    for (int j = 1; j < 8; ++j) s10[2*j] = s1[j-1] * la[2*j] + lb[2*j];
  }

  // pass 2: chunk_down per chunk (re-read L5 from L2)
#pragma unroll 1
  for (int c = 0; c < 16; ++c) {
    const bool hasP = (c > 0);
    const float P = hasP ? s10[c - 1] : 0.0f;
    const float S = s10[c];
    const unsigned cbase = (unsigned)(c * 32) << 8;

    float ae[16], be[16], a1[16], b1[16];
#pragma unroll
    for (int i = 0; i < 16; ++i) {
      f32x2 e0 = src[cbase + ((unsigned)(2 * i) << 8)];
      f32x2 e1 = src[cbase + ((unsigned)(2 * i + 1) << 8)];
      ae[i] = e0[0]; be[i] = e0[1];
      a1[i] = e0[0] * e0[1];
      b1[i] = e0[1] * e1[0] + e1[1];
    }
    float a2[8], b2[8];
#pragma unroll
    for (int i = 0; i < 8; ++i) { a2[i] = a1[2*i]*b1[2*i]; b2[i] = b1[2*i]*a1[2*i+1] + b1[2*i+1]; }
    float a3[4], b3[4];
#pragma unroll
    for (int i = 0; i < 4; ++i) { a3[i] = a2[2*i]*b2[2*i]; b3[i] = b2[2*i]*a2[2*i+1] + b2[2*i+1]; }
    float a4[2], b4[2];
#pragma unroll
    for (int i = 0; i < 2; ++i) { a4[i] = a3[2*i]*b3[2*i]; b4[i] = b3[2*i]*a3[2*i+1] + b3[2*i+1]; }

    float s4[2];
    s4[0] = hasP ? P * a4[0] + b4[0] : b4[0];
    s4[1] = S;
    float s3[4];
    s3[0] = hasP ? P * a3[0] + b3[0] : b3[0];
    s3[1] = s4[0]; s3[2] = s4[0] * a3[2] + b3[2]; s3[3] = s4[1];
    float s2[8];
    s2[0] = hasP ? P * a2[0] + b2[0] : b2[0];
#pragma unroll
    for (int j = 0; j < 4; ++j) s2[2*j+1] = s3[j];
#pragma unroll
    for (int j = 1; j < 4; ++j) s2[2*j] = s3[j-1] * a2[2*j] + b2[2*j];
    float s1[16];
    s1[0] = hasP ? P * a1[0] + b1[0] : b1[0];
#pragma unroll
    for (int j = 0; j < 8; ++j) s1[2*j+1] = s2[j];
#pragma unroll
    for (int j = 1; j < 8; ++j) s1[2*j] = s2[j-1] * a1[2*j] + b1[2*j];

    dst[cbase] = hasP ? P * ae[0] + be[0] : be[0];
#pragma unroll
    for (int j = 0; j < 16; ++j) dst[cbase + ((unsigned)(2*j+1) << 8)] = s1[j];
#pragma unroll
    for (int j = 1; j < 16; ++j) dst[cbase + ((unsigned)(2*j) << 8)] = s1[j-1] * ae[j] + be[j];
  }
}

// ---------------------------------------------------------------- fused L0 down-sweep + output projection (32-bit addressing)
__global__ __launch_bounds__(256, 2)
void down_proj(const unsigned* __restrict__ l0, const float* __restrict__ s5b,
               const unsigned short* __restrict__ wo_t, const float* __restrict__ bo,
               float* __restrict__ out)
{
  __shared__ unsigned short pL[32 * 256];   // [row][h], h XOR-swizzled by ((row&7)<<3)

  const int tid = threadIdx.x;
  const int bc = blockIdx.x;
  const int c = bc % 513;
  const int batch = bc / 513;

  const unsigned* const l0b = l0 + (size_t)batch * (NL0 * 256);
  const float* const s5bb = s5b + (size_t)batch * (512 * 256);
  float* const outb = out + (size_t)batch * (Tsz * 256);

  {  // ---- scan phase: thread = h
    const int h = tid;
    const unsigned base = ((unsigned)(c * 32) << 8) + (unsigned)h;
    const bool hasP = (c > 0);
    const float P = hasP ? s5bb[((unsigned)(c - 1) << 8) + h] : 0.0f;

    if (c == 512) {                          // single tail element (t = 16383)
      float a0, b0; unpk(l0b[base], a0, b0);
      pL[h] = (unsigned short)f2bf(P * a0 + b0);
#pragma unroll
      for (int i = 1; i < 32; ++i)
        pL[i * 256 + (h ^ ((i & 7) << 3))] = 0;
    } else {
      const float S = s5bb[((unsigned)c << 8) + h];
      float ae[16], be[16], a1[16], b1[16];
#pragma unroll
      for (int i = 0; i < 16; ++i) {
        unsigned u0 = l0b[base + ((unsigned)(2 * i) << 8)];
        unsigned u1 = l0b[base + ((unsigned)(2 * i + 1) << 8)];
        float a0, b0, a1e, b1e;
        unpk(u0, a0, b0); unpk(u1, a1e, b1e);
        ae[i] = a0; be[i] = b0;
        a1[i] = a0 * b0; b1[i] = b0 * a1e + b1e;
      }
      float a2[8], b2[8];
#pragma unroll
      for (int i = 0; i < 8; ++i) { a2[i] = a1[2*i]*b1[2*i]; b2[i] = b1[2*i]*a1[2*i+1] + b1[2*i+1]; }
      float a3[4], b3[4];
#pragma unroll
      for (int i = 0; i < 4; ++i) { a3[i] = a2[2*i]*b2[2*i]; b3[i] = b2[2*i]*a2[2*i+1] + b2[2*i+1]; }
      float a4[2], b4[2];
#pragma unroll
      for (int i = 0; i < 2; ++i) { a4[i] = a3[2*i]*b3[2*i]; b4[i] = b3[2*i]*a3[2*i+1] + b3[2*i+1]; }

      float s4[2];
      s4[0] = hasP ? P * a4[0] + b4[0] : b4[0];
      s4[1] = S;
      float s3[4];
      s3[0] = hasP ? P * a3[0] + b3[0] : b3[0];
      s3[1] = s4[0]; s3[2] = s4[0] * a3[2] + b3[2]; s3[3] = s4[1];
      float s2[8];
      s2[0] = hasP ? P * a2[0] + b2[0] : b2[0];
#pragma unroll
      for (int j = 0; j < 4; ++j) s2[2*j+1] = s3[j];
#pragma unroll
      for (int j = 1; j < 4; ++j) s2[2*j] = s3[j-1] * a2[2*j] + b2[2*j];
      float s1[16];
      s1[0] = hasP ? P * a1[0] + b1[0] : b1[0];
#pragma unroll
      for (int j = 0; j < 8; ++j) s1[2*j+1] = s2[j];
#pragma unroll
      for (int j = 1; j < 8; ++j) s1[2*j] = s2[j-1] * a1[2*j] + b1[2*j];

      pL[h] = (unsigned short)f2bf(hasP ? P * ae[0] + be[0] : be[0]);
#pragma unroll
      for (int j = 0; j < 16; ++j) {
        const int row = 2 * j + 1;
        pL[row * 256 + (h ^ ((row & 7) << 3))] = (unsigned short)f2bf(s1[j]);
      }
#pragma unroll
      for (int j = 1; j < 16; ++j) {
        const int row = 2 * j;
        pL[row * 256 + (h ^ ((row & 7) << 3))] = (unsigned short)f2bf(s1[j-1] * ae[j] + be[j]);
      }
    }
  }
  __syncthreads();

  // ---- projection phase: M=32, N=64/wave, K=256; Wo frags from L2, pipelined
  const int wave = tid >> 6, lane = tid & 63, l15 = lane & 15, l4 = lane >> 4;
  const int wn = wave * 64;
  f32x4 acc[2][4] = {};
  bf16x8 wc[4], wnx[4];
#pragma unroll
  for (int n = 0; n < 4; ++n)
    wc[n] = *(const bf16x8*)(wo_t + (l4 * 256 + wn + n * 16 + l15) * 8);   // kk=0
#pragma unroll
  for (int kk = 0; kk < 8; ++kk) {
    if (kk < 7) {
#pragma unroll
      for (int n = 0; n < 4; ++n)
        wnx[n] = *(const bf16x8*)(wo_t + (((kk + 1) * 4 + l4) * 256 + wn + n * 16 + l15) * 8);
    }
    bf16x8 af[2];
#pragma unroll
    for (int m = 0; m < 2; ++m) {
      const int row = m * 16 + l15;
      af[m] = *(const bf16x8*)&pL[row * 256 + ((kk * 32 + l4 * 8) ^ ((row & 7) << 3))];
    }
#pragma unroll
    for (int m = 0; m < 2; ++m)
#pragma unroll
      for (int n = 0; n < 4; ++n)
        acc[m][n] = __builtin_amdgcn_mfma_f32_16x16x32_bf16(af[m], wc[n], acc[m][n], 0, 0, 0);
    if (kk < 7) {
      wc[0] = wnx[0]; wc[1] = wnx[1]; wc[2] = wnx[2]; wc[3] = wnx[3];
    }
  }

  const int tBase = 32 * c - 1;
#pragma unroll
  for (int n = 0; n < 4; ++n) {
    const int col = wn + n * 16 + l15;
    const float bv = bo[col];
#pragma unroll
    for (int m = 0; m < 2; ++m)
#pragma unroll
      for (int j = 0; j < 4; ++j) {
        const int t = tBase + m * 16 + l4 * 4 + j;
        if ((unsigned)t < (unsigned)Tsz)
          outb[((unsigned)t << 8) + (unsigned)col] = acc[m][n][j] + bv;
      }
  }
}

// ================================================================ host
extern "C" void kernel_launch(void* const* d_in, const int* in_sizes, int n_in,
                              void* d_out, int out_size, void* d_ws, size_t ws_size,
                              hipStream_t stream)
{
  (void)in_sizes; (void)n_in;
  const float* xs = (const float*)d_in[0];
  const float* Wz = (const float*)d_in[1];
  const float* bz = (const float*)d_in[2];
  const float* Wh = (const float*)d_in[3];
  const float* bh = (const float*)d_in[4];
  const float* Wo = (const float*)d_in[5];
  const float* bo = (const float*)d_in[6];
  float* out = (float*)d_out;

  const size_t n_l0 = (size_t)Bsz * NL0 * 256;
  const size_t n_l5 = (size_t)Bsz * NL5 * 256;

  unsigned* l0    = (unsigned*)d_ws;
  f32x2* l5ab     = (f32x2*)(l0 + n_l0);
  float* s5b      = (float*)(l5ab + n_l5);
  unsigned short* wt = (unsigned short*)(s5b + n_l5);

  const size_t need = n_l0 * 4 + n_l5 * 8 + n_l5 * 4 + 3 * 65536 * 2;
  if (ws_size < need) {
    fill_sentinel<<<(out_size + 255) / 256, 256, 0, stream>>>(out, out_size);
    return;
  }

  prep_weights<<<96, 256, 0, stream>>>(Wz, Wh, Wo, wt);
  gemm_zh<<<Bsz * 513, 256, 0, stream>>>(xs, wt, bz, bh, l0, l5ab);
  mid_scan<<<Bsz, 256, 0, stream>>>(l5ab, s5b);
  down_proj<<<Bsz * 513, 256, 0, stream>>>(l0, s5b, wt + 2 * 65536, bo, out);
}

// Round 14
// 166.708 us; speedup vs baseline: 1.1664x; 1.1664x over previous
//
#include <hip/hip_runtime.h>
#include <hip/hip_bf16.h>

#define Bsz 8
#define Tsz 16384
#define NL0 16385
#define NL5 512
#define NL10 16

typedef __attribute__((ext_vector_type(2))) float f32x2;
typedef __attribute__((ext_vector_type(4))) float f32x4;
typedef __attribute__((ext_vector_type(8))) short bf16x8;

__device__ __forceinline__ short f2bf(float f) {
  unsigned u = __builtin_bit_cast(unsigned, f);
  u += 0x7FFFu + ((u >> 16) & 1u);
  return (short)(u >> 16);
}
__device__ __forceinline__ unsigned cvtpk(float lo, float hi) {
  __hip_bfloat162 t = __float22bfloat162_rn(float2{lo, hi});
  unsigned u;
  __builtin_memcpy(&u, &t, 4);
  return u;
}
__device__ __forceinline__ bf16x8 pack8(f32x4 a, f32x4 b) {
  union { unsigned u[4]; bf16x8 v; } r;
  r.u[0] = cvtpk(a[0], a[1]); r.u[1] = cvtpk(a[2], a[3]);
  r.u[2] = cvtpk(b[0], b[1]); r.u[3] = cvtpk(b[2], b[3]);
  return r.v;
}
__device__ __forceinline__ void unpk(unsigned u, float& a, float& b) {
  a = __builtin_bit_cast(float, u << 16);
  b = __builtin_bit_cast(float, u & 0xFFFF0000u);
}

// ---------------------------------------------------------------- sentinel
__global__ void fill_sentinel(float* __restrict__ out, int n) {
  int i = blockIdx.x * blockDim.x + threadIdx.x;
  if (i < n) out[i] = 12345.0f;
}

// ---------------------------------------------------------------- weight prep: fp32 [256][256] -> bf16 tiled [c/8][r][c%8]
__global__ void prep_weights(const float* __restrict__ Wz, const float* __restrict__ Wh,
                             const float* __restrict__ Wo, unsigned short* __restrict__ wt) {
  int idx = blockIdx.x * 256 + threadIdx.x;          // 3 * 256 * 32
  if (idx >= 3 * 256 * 32) return;
  int m   = idx >> 13;
  int rem = idx & 8191;
  int r   = rem >> 5;
  int cq  = rem & 31;
  const float* src = (m == 0 ? Wz : (m == 1 ? Wh : Wo)) + r * 256 + cq * 8;
  f32x4 v0 = *(const f32x4*)src;
  f32x4 v1 = *(const f32x4*)(src + 4);
  *(bf16x8*)(wt + m * 65536 + (cq * 256 + r) * 8) = pack8(v0, v1);
}

// ---------------------------------------------------------------- GEMM 1 + fused chunk up-sweep (32-bit addressing)
__global__ __launch_bounds__(256, 3)
void gemm_zh(const float* __restrict__ xs, const unsigned short* __restrict__ wt,
             const float* __restrict__ bz, const float* __restrict__ bh,
             unsigned* __restrict__ l0, f32x2* __restrict__ l5)
{
  __shared__ __align__(16) unsigned short aL[32][32][8];  // [row][oct^(row&7)][8] = 16 KB

  const int tid = threadIdx.x;
  const int wave = tid >> 6, lane = tid & 63, l15 = lane & 15, l4 = lane >> 4;
  const int bid = blockIdx.x;
  const int batch = bid / 513;
  const int cb = bid - batch * 513;
  const unsigned short* wz_t = wt;
  const unsigned short* wh_t = wt + 65536;
  const int wn = wave * 64;

  unsigned* const l0b = l0 + (size_t)batch * (NL0 * 256);
  f32x2* const l5b = l5 + (size_t)batch * (512 * 256);

  {
    const int gr0i = batch * Tsz + 32 * cb - 1;          // xs row of LDS row 0
    const int rowsMax = Bsz * Tsz - 1;
    f32x4 av0[4], av1[4];
#pragma unroll
    for (int k = 0; k < 4; ++k) {
      const int row = (tid >> 5) + k * 8;
      const int col = (tid & 31) * 8;
      int gr = gr0i + row;
      gr = gr < 0 ? 0 : (gr > rowsMax ? rowsMax : gr);
      const float* p = xs + (((unsigned)gr << 8) + (unsigned)col);
      av0[k] = *(const f32x4*)p;
      av1[k] = *(const f32x4*)(p + 4);
    }
#pragma unroll
    for (int k = 0; k < 4; ++k) {
      const int o = tid + k * 256;          // flat octet = row*32 + oct
      const int row = o >> 5, oct = o & 31;
      *(bf16x8*)&aL[row][oct ^ (row & 7)][0] = pack8(av0[k], av1[k]);
    }
  }
  __syncthreads();

  f32x4 accz[2][4] = {};
  f32x4 acch[2][4] = {};

#pragma unroll
  for (int kk = 0; kk < 8; ++kk) {                       // K=32 per step
    bf16x8 af[2];
#pragma unroll
    for (int m = 0; m < 2; ++m) {
      const int row = m * 16 + l15;
      af[m] = *(const bf16x8*)&aL[row][(kk * 4 + l4) ^ (row & 7)][0];
    }
    const int cq = kk * 4 + l4;
    bf16x8 zf[4], hf[4];
#pragma unroll
    for (int n = 0; n < 4; ++n) {
      const int r = wn + n * 16 + l15;
      zf[n] = *(const bf16x8*)(wz_t + (cq * 256 + r) * 8);
      hf[n] = *(const bf16x8*)(wh_t + (cq * 256 + r) * 8);
    }
#pragma unroll
    for (int m = 0; m < 2; ++m)
#pragma unroll
      for (int n = 0; n < 4; ++n) {
        accz[m][n] = __builtin_amdgcn_mfma_f32_16x16x32_bf16(af[m], zf[n], accz[m][n], 0, 0, 0);
        acch[m][n] = __builtin_amdgcn_mfma_f32_16x16x32_bf16(af[m], hf[n], acch[m][n], 0, 0, 0);
      }
  }

  // ---- epilogue: (a,b), identity override, l0 write (32-bit offsets), reduce
  const unsigned base0 = ((unsigned)(32 * cb) << 8) + (unsigned)(wn + l15) + ((unsigned)l4 << 10);
#pragma unroll
  for (int n = 0; n < 4; ++n) {
    const int col = wn + n * 16 + l15;
    const float bzv = bz[col], bhv = bh[col];
#pragma unroll
    for (int m = 0; m < 2; ++m)
#pragma unroll
      for (int j = 0; j < 4; ++j) {
        const int e = m * 16 + l4 * 4 + j;               // slot within chunk
        const float zv = 1.0f / (1.0f + __expf(-(accz[m][n][j] + bzv)));
        const float hv = acch[m][n][j] + bhv;
        float a = 1.0f - zv, b = zv * hv;
        if (cb == 0 && e == 0) { a = 1.0f; b = 0.0f; }   // prepended identity
        const unsigned u = cvtpk(a, b);
        if (cb < 512 || e == 0)
          l0b[base0 + (unsigned)(n * 16 + m * 4096 + j * 256)] = u;
        float ar, br; unpk(u, ar, br);
        accz[m][n][j] = ar; acch[m][n][j] = br;
      }
  }

  if (cb < 512) {
    const bool f3 = (l4 & 1) == 0;
    const bool f4 = (l4 & 2) == 0;
#pragma unroll
    for (int n = 0; n < 4; ++n) {
      float a4v[2], b4v[2];
#pragma unroll
      for (int m = 0; m < 2; ++m) {
        const float a10 = accz[m][n][0] * acch[m][n][0];
        const float b10 = acch[m][n][0] * accz[m][n][1] + acch[m][n][1];
        const float a11 = accz[m][n][2] * acch[m][n][2];
        const float b11 = acch[m][n][2] * accz[m][n][3] + acch[m][n][3];
        const float a2 = a10 * b10;
        const float b2 = b10 * a11 + b11;
        const float pa = __shfl_xor(a2, 16);
        const float pb = __shfl_xor(b2, 16);
        const float a3 = f3 ? a2 * b2 : pa * pb;
        const float b3 = f3 ? b2 * pa + pb : pb * a2 + b2;
        const float qa = __shfl_xor(a3, 32);
        const float qb = __shfl_xor(b3, 32);
        a4v[m] = f4 ? a3 * b3 : qa * qb;
        b4v[m] = f4 ? b3 * qa + qb : qb * a3 + b3;
      }
      const float a5 = a4v[0] * b4v[0];
      const float b5 = b4v[0] * a4v[1] + b4v[1];
      if (l4 == 0)
        l5b[((unsigned)cb << 8) + (unsigned)(wn + n * 16 + l15)] = f32x2{a5, b5};
    }
  }
}

// ---------------------------------------------------------------- chunk up-sweep f32 (L5 -> L10), 128 blocks
__global__ __launch_bounds__(256)
void chunk_up(const f32x2* __restrict__ src, f32x2* __restrict__ dst, int nCh, int nSrc)
{
  int idx = blockIdx.x * 256 + threadIdx.x;
  int total = Bsz * nCh * 256;
  if (idx >= total) return;
  int h = idx & 255, r = idx >> 8;
  int c = r % nCh, batch = r / nCh;
  size_t base = ((size_t)batch * nSrc + (size_t)c * 32) * 256 + h;

  float a1[16], b1[16];
#pragma unroll
  for (int i = 0; i < 16; ++i) {
    f32x2 e0 = src[base + (size_t)(2 * i) * 256];
    f32x2 e1 = src[base + (size_t)(2 * i + 1) * 256];
    a1[i] = e0[0] * e0[1];
    b1[i] = e0[1] * e1[0] + e1[1];
  }
#pragma unroll
  for (int n = 8; n >= 1; n >>= 1) {
#pragma unroll
    for (int i = 0; i < n; ++i) {
      float na = a1[2 * i] * b1[2 * i];
      float nb = b1[2 * i] * a1[2 * i + 1] + b1[2 * i + 1];
      a1[i] = na; b1[i] = nb;
    }
  }
  dst[((size_t)batch * nCh + c) * 256 + h] = f32x2{a1[0], b1[0]};
}

// ---------------------------------------------------------------- 16-element full tree scan (top levels), exact b-scan
__global__ void tree16(const f32x2* __restrict__ src, float* __restrict__ outB)
{
  int idx = blockIdx.x * 256 + threadIdx.x;
  if (idx >= Bsz * 256) return;
  int h = idx & 255, batch = idx >> 8;
  size_t base = (size_t)batch * 16 * 256 + h;

  float a0[16], b0[16];
#pragma unroll
  for (int i = 0; i < 16; ++i) { f32x2 e = src[base + (size_t)i * 256]; a0[i] = e[0]; b0[i] = e[1]; }
  float a1[8], b1[8];
#pragma unroll
  for (int i = 0; i < 8; ++i) { a1[i] = a0[2*i]*b0[2*i]; b1[i] = b0[2*i]*a0[2*i+1] + b0[2*i+1]; }
  float a2[4], b2[4];
#pragma unroll
  for (int i = 0; i < 4; ++i) { a2[i] = a1[2*i]*b1[2*i]; b2[i] = b1[2*i]*a1[2*i+1] + b1[2*i+1]; }
  float a3[2], b3[2];
#pragma unroll
  for (int i = 0; i < 2; ++i) { a3[i] = a2[2*i]*b2[2*i]; b3[i] = b2[2*i]*a2[2*i+1] + b2[2*i+1]; }
  float s3[2];
  s3[0] = b3[0];
  s3[1] = b3[0] * a3[1] + b3[1];
  float s2[4];
  s2[0] = b2[0]; s2[1] = s3[0]; s2[2] = s3[0] * a2[2] + b2[2]; s2[3] = s3[1];
  float s1[8];
  s1[0] = b1[0];
#pragma unroll
  for (int j = 0; j < 4; ++j) s1[2*j+1] = s2[j];
#pragma unroll
  for (int j = 1; j < 4; ++j) s1[2*j] = s2[j-1] * a1[2*j] + b1[2*j];
  float s0[16];
  s0[0] = b0[0];
#pragma unroll
  for (int j = 0; j < 8; ++j) s0[2*j+1] = s1[j];
#pragma unroll
  for (int j = 1; j < 8; ++j) s0[2*j] = s1[j-1] * a0[2*j] + b0[2*j];
#pragma unroll
  for (int i = 0; i < 16; ++i) outB[base + (size_t)i * 256] = s0[i];
}

// ---------------------------------------------------------------- chunk down-sweep f32 (L5 level): needs P=snext[c-1], S=snext[c]
__global__ __launch_bounds__(256, 2)
void chunk_down_f32(const f32x2* __restrict__ src, const float* __restrict__ snext,
                    float* __restrict__ outF, int nCh, int nFull, int nSrc)
{
  int idx = blockIdx.x * 256 + threadIdx.x;
  int total = Bsz * nCh * 256;
  if (idx >= total) return;
  int h = idx & 255, r = idx >> 8;
  int c = r % nCh, batch = r / nCh;
  size_t base = ((size_t)batch * nSrc + (size_t)c * 32) * 256 + h;
  bool hasP = (c > 0);
  float P = hasP ? snext[((size_t)batch * nFull + (c - 1)) * 256 + h] : 0.0f;
  float S = snext[((size_t)batch * nFull + c) * 256 + h];

  float ae[16], be[16], a1[16], b1[16];
#pragma unroll
  for (int i = 0; i < 16; ++i) {
    f32x2 e0 = src[base + (size_t)(2 * i) * 256];
    f32x2 e1 = src[base + (size_t)(2 * i + 1) * 256];
    ae[i] = e0[0]; be[i] = e0[1];
    a1[i] = e0[0] * e0[1];
    b1[i] = e0[1] * e1[0] + e1[1];
  }
  float a2[8], b2[8];
#pragma unroll
  for (int i = 0; i < 8; ++i) { a2[i] = a1[2*i]*b1[2*i]; b2[i] = b1[2*i]*a1[2*i+1] + b1[2*i+1]; }
  float a3[4], b3[4];
#pragma unroll
  for (int i = 0; i < 4; ++i) { a3[i] = a2[2*i]*b2[2*i]; b3[i] = b2[2*i]*a2[2*i+1] + b2[2*i+1]; }
  float a4[2], b4[2];
#pragma unroll
  for (int i = 0; i < 2; ++i) { a4[i] = a3[2*i]*b3[2*i]; b4[i] = b3[2*i]*a3[2*i+1] + b3[2*i+1]; }

  float s4[2];
  s4[0] = hasP ? P * a4[0] + b4[0] : b4[0];
  s4[1] = S;
  float s3[4];
  s3[0] = hasP ? P * a3[0] + b3[0] : b3[0];
  s3[1] = s4[0]; s3[2] = s4[0] * a3[2] + b3[2]; s3[3] = s4[1];
  float s2[8];
  s2[0] = hasP ? P * a2[0] + b2[0] : b2[0];
#pragma unroll
  for (int j = 0; j < 4; ++j) s2[2*j+1] = s3[j];
#pragma unroll
  for (int j = 1; j < 4; ++j) s2[2*j] = s3[j-1] * a2[2*j] + b2[2*j];
  float s1[16];
  s1[0] = hasP ? P * a1[0] + b1[0] : b1[0];
#pragma unroll
  for (int j = 0; j < 8; ++j) s1[2*j+1] = s2[j];
#pragma unroll
  for (int j = 1; j < 8; ++j) s1[2*j] = s2[j-1] * a1[2*j] + b1[2*j];

  outF[base] = hasP ? P * ae[0] + be[0] : be[0];
#pragma unroll
  for (int j = 0; j < 16; ++j) outF[base + (size_t)(2*j+1) * 256] = s1[j];
#pragma unroll
  for (int j = 1; j < 16; ++j) outF[base + (size_t)(2*j) * 256] = s1[j-1] * ae[j] + be[j];
}

// ---------------------------------------------------------------- fused L0 down-sweep + output projection (32-bit addressing)
__global__ __launch_bounds__(256, 2)
void down_proj(const unsigned* __restrict__ l0, const float* __restrict__ s5b,
               const unsigned short* __restrict__ wo_t, const float* __restrict__ bo,
               float* __restrict__ out)
{
  __shared__ unsigned short pL[32 * 256];   // [row][h], h XOR-swizzled by ((row&7)<<3)

  const int tid = threadIdx.x;
  const int bc = blockIdx.x;
  const int c = bc % 513;
  const int batch = bc / 513;

  const unsigned* const l0b = l0 + (size_t)batch * (NL0 * 256);
  const float* const s5bb = s5b + (size_t)batch * (512 * 256);
  float* const outb = out + (size_t)batch * (Tsz * 256);

  {  // ---- scan phase: thread = h
    const int h = tid;
    const unsigned base = ((unsigned)(c * 32) << 8) + (unsigned)h;
    const bool hasP = (c > 0);
    const float P = hasP ? s5bb[((unsigned)(c - 1) << 8) + h] : 0.0f;

    if (c == 512) {                          // single tail element (t = 16383)
      float a0, b0; unpk(l0b[base], a0, b0);
      pL[h] = (unsigned short)f2bf(P * a0 + b0);
#pragma unroll
      for (int i = 1; i < 32; ++i)
        pL[i * 256 + (h ^ ((i & 7) << 3))] = 0;
    } else {
      const float S = s5bb[((unsigned)c << 8) + h];
      float ae[16], be[16], a1[16], b1[16];
#pragma unroll
      for (int i = 0; i < 16; ++i) {
        unsigned u0 = l0b[base + ((unsigned)(2 * i) << 8)];
        unsigned u1 = l0b[base + ((unsigned)(2 * i + 1) << 8)];
        float a0, b0, a1e, b1e;
        unpk(u0, a0, b0); unpk(u1, a1e, b1e);
        ae[i] = a0; be[i] = b0;
        a1[i] = a0 * b0; b1[i] = b0 * a1e + b1e;
      }
      float a2[8], b2[8];
#pragma unroll
      for (int i = 0; i < 8; ++i) { a2[i] = a1[2*i]*b1[2*i]; b2[i] = b1[2*i]*a1[2*i+1] + b1[2*i+1]; }
      float a3[4], b3[4];
#pragma unroll
      for (int i = 0; i < 4; ++i) { a3[i] = a2[2*i]*b2[2*i]; b3[i] = b2[2*i]*a2[2*i+1] + b2[2*i+1]; }
      float a4[2], b4[2];
#pragma unroll
      for (int i = 0; i < 2; ++i) { a4[i] = a3[2*i]*b3[2*i]; b4[i] = b3[2*i]*a3[2*i+1] + b3[2*i+1]; }

      float s4[2];
      s4[0] = hasP ? P * a4[0] + b4[0] : b4[0];
      s4[1] = S;
      float s3[4];
      s3[0] = hasP ? P * a3[0] + b3[0] : b3[0];
      s3[1] = s4[0]; s3[2] = s4[0] * a3[2] + b3[2]; s3[3] = s4[1];
      float s2[8];
      s2[0] = hasP ? P * a2[0] + b2[0] : b2[0];
#pragma unroll
      for (int j = 0; j < 4; ++j) s2[2*j+1] = s3[j];
#pragma unroll
      for (int j = 1; j < 4; ++j) s2[2*j] = s3[j-1] * a2[2*j] + b2[2*j];
      float s1[16];
      s1[0] = hasP ? P * a1[0] + b1[0] : b1[0];
#pragma unroll
      for (int j = 0; j < 8; ++j) s1[2*j+1] = s2[j];
#pragma unroll
      for (int j = 1; j < 8; ++j) s1[2*j] = s2[j-1] * a1[2*j] + b1[2*j];

      pL[h] = (unsigned short)f2bf(hasP ? P * ae[0] + be[0] : be[0]);
#pragma unroll
      for (int j = 0; j < 16; ++j) {
        const int row = 2 * j + 1;
        pL[row * 256 + (h ^ ((row & 7) << 3))] = (unsigned short)f2bf(s1[j]);
      }
#pragma unroll
      for (int j = 1; j < 16; ++j) {
        const int row = 2 * j;
        pL[row * 256 + (h ^ ((row & 7) << 3))] = (unsigned short)f2bf(s1[j-1] * ae[j] + be[j]);
      }
    }
  }
  __syncthreads();

  // ---- projection phase: M=32, N=64/wave, K=256; Wo frags from L2, pipelined
  const int wave = tid >> 6, lane = tid & 63, l15 = lane & 15, l4 = lane >> 4;
  const int wn = wave * 64;
  f32x4 acc[2][4] = {};
  bf16x8 wc[4], wnx[4];
#pragma unroll
  for (int n = 0; n < 4; ++n)
    wc[n] = *(const bf16x8*)(wo_t + (l4 * 256 + wn + n * 16 + l15) * 8);   // kk=0
#pragma unroll
  for (int kk = 0; kk < 8; ++kk) {
    if (kk < 7) {
#pragma unroll
      for (int n = 0; n < 4; ++n)
        wnx[n] = *(const bf16x8*)(wo_t + (((kk + 1) * 4 + l4) * 256 + wn + n * 16 + l15) * 8);
    }
    bf16x8 af[2];
#pragma unroll
    for (int m = 0; m < 2; ++m) {
      const int row = m * 16 + l15;
      af[m] = *(const bf16x8*)&pL[row * 256 + ((kk * 32 + l4 * 8) ^ ((row & 7) << 3))];
    }
#pragma unroll
    for (int m = 0; m < 2; ++m)
#pragma unroll
      for (int n = 0; n < 4; ++n)
        acc[m][n] = __builtin_amdgcn_mfma_f32_16x16x32_bf16(af[m], wc[n], acc[m][n], 0, 0, 0);
    if (kk < 7) {
      wc[0] = wnx[0]; wc[1] = wnx[1]; wc[2] = wnx[2]; wc[3] = wnx[3];
    }
  }

  const int tBase = 32 * c - 1;
#pragma unroll
  for (int n = 0; n < 4; ++n) {
    const int col = wn + n * 16 + l15;
    const float bv = bo[col];
#pragma unroll
    for (int m = 0; m < 2; ++m)
#pragma unroll
      for (int j = 0; j < 4; ++j) {
        const int t = tBase + m * 16 + l4 * 4 + j;
        if ((unsigned)t < (unsigned)Tsz)
          outb[((unsigned)t << 8) + (unsigned)col] = acc[m][n][j] + bv;
      }
  }
}

// ================================================================ host
extern "C" void kernel_launch(void* const* d_in, const int* in_sizes, int n_in,
                              void* d_out, int out_size, void* d_ws, size_t ws_size,
                              hipStream_t stream)
{
  (void)in_sizes; (void)n_in;
  const float* xs = (const float*)d_in[0];
  const float* Wz = (const float*)d_in[1];
  const float* bz = (const float*)d_in[2];
  const float* Wh = (const float*)d_in[3];
  const float* bh = (const float*)d_in[4];
  const float* Wo = (const float*)d_in[5];
  const float* bo = (const float*)d_in[6];
  float* out = (float*)d_out;

  const size_t n_l0  = (size_t)Bsz * NL0 * 256;
  const size_t n_l5  = (size_t)Bsz * NL5 * 256;
  const size_t n_l10 = (size_t)Bsz * NL10 * 256;

  unsigned* l0    = (unsigned*)d_ws;
  f32x2* l5ab     = (f32x2*)(l0 + n_l0);
  f32x2* l10ab    = l5ab + n_l5;
  float* s10b     = (float*)(l10ab + n_l10);
  float* s5b      = s10b + n_l10;
  unsigned short* wt = (unsigned short*)(s5b + n_l5);

  const size_t need = n_l0 * 4 + n_l5 * 8 + n_l10 * 8 + n_l10 * 4 + n_l5 * 4 + 3 * 65536 * 2;
  if (ws_size < need) {
    fill_sentinel<<<(out_size + 255) / 256, 256, 0, stream>>>(out, out_size);
    return;
  }

  prep_weights<<<96, 256, 0, stream>>>(Wz, Wh, Wo, wt);
  gemm_zh<<<Bsz * 513, 256, 0, stream>>>(xs, wt, bz, bh, l0, l5ab);
  chunk_up<<<(Bsz * 16 * 256) / 256, 256, 0, stream>>>(l5ab, l10ab, 16, NL5);
  tree16<<<8, 256, 0, stream>>>(l10ab, s10b);
  chunk_down_f32<<<(Bsz * 16 * 256) / 256, 256, 0, stream>>>(l5ab, s10b, s5b, 16, 16, NL5);
  down_proj<<<Bsz * 513, 256, 0, stream>>>(l0, s5b, wt + 2 * 65536, bo, out);
}

// Round 15
// 166.126 us; speedup vs baseline: 1.1705x; 1.0035x over previous
//
#include <hip/hip_runtime.h>
#include <hip/hip_bf16.h>

#define Bsz 8
#define Tsz 16384
#define NL0 16385
#define NL5 512
#define NL10 16

typedef __attribute__((ext_vector_type(2))) float f32x2;
typedef __attribute__((ext_vector_type(4))) float f32x4;
typedef __attribute__((ext_vector_type(8))) short bf16x8;

__device__ __forceinline__ short f2bf(float f) {
  unsigned u = __builtin_bit_cast(unsigned, f);
  u += 0x7FFFu + ((u >> 16) & 1u);
  return (short)(u >> 16);
}
__device__ __forceinline__ unsigned cvtpk(float lo, float hi) {
  __hip_bfloat162 t = __float22bfloat162_rn(float2{lo, hi});
  unsigned u;
  __builtin_memcpy(&u, &t, 4);
  return u;
}
__device__ __forceinline__ bf16x8 pack8(f32x4 a, f32x4 b) {
  union { unsigned u[4]; bf16x8 v; } r;
  r.u[0] = cvtpk(a[0], a[1]); r.u[1] = cvtpk(a[2], a[3]);
  r.u[2] = cvtpk(b[0], b[1]); r.u[3] = cvtpk(b[2], b[3]);
  return r.v;
}
__device__ __forceinline__ void unpk(unsigned u, float& a, float& b) {
  a = __builtin_bit_cast(float, u << 16);
  b = __builtin_bit_cast(float, u & 0xFFFF0000u);
}

// ---------------------------------------------------------------- sentinel
__global__ void fill_sentinel(float* __restrict__ out, int n) {
  int i = blockIdx.x * blockDim.x + threadIdx.x;
  if (i < n) out[i] = 12345.0f;
}

// ---------------------------------------------------------------- weight prep: fp32 [256][256] -> bf16 tiled [c/8][r][c%8]
__global__ void prep_weights(const float* __restrict__ Wz, const float* __restrict__ Wh,
                             const float* __restrict__ Wo, unsigned short* __restrict__ wt) {
  int idx = blockIdx.x * 256 + threadIdx.x;          // 3 * 256 * 32
  if (idx >= 3 * 256 * 32) return;
  int m   = idx >> 13;
  int rem = idx & 8191;
  int r   = rem >> 5;
  int cq  = rem & 31;
  const float* src = (m == 0 ? Wz : (m == 1 ? Wh : Wo)) + r * 256 + cq * 8;
  f32x4 v0 = *(const f32x4*)src;
  f32x4 v1 = *(const f32x4*)(src + 4);
  *(bf16x8*)(wt + m * 65536 + (cq * 256 + r) * 8) = pack8(v0, v1);
}

// ---------------------------------------------------------------- GEMM 1 + fused chunk up-sweep (32-bit addressing)
__global__ __launch_bounds__(256, 3)
void gemm_zh(const float* __restrict__ xs, const unsigned short* __restrict__ wt,
             const float* __restrict__ bz, const float* __restrict__ bh,
             unsigned* __restrict__ l0, f32x2* __restrict__ l5)
{
  __shared__ __align__(16) unsigned short aL[32][32][8];  // [row][oct^(row&7)][8] = 16 KB

  const int tid = threadIdx.x;
  const int wave = tid >> 6, lane = tid & 63, l15 = lane & 15, l4 = lane >> 4;
  const int bid = blockIdx.x;
  const int batch = bid / 513;
  const int cb = bid - batch * 513;
  const unsigned short* wz_t = wt;
  const unsigned short* wh_t = wt + 65536;
  const int wn = wave * 64;

  unsigned* const l0b = l0 + (size_t)batch * (NL0 * 256);
  f32x2* const l5b = l5 + (size_t)batch * (512 * 256);

  {
    const int gr0i = batch * Tsz + 32 * cb - 1;          // xs row of LDS row 0
    const int rowsMax = Bsz * Tsz - 1;
    f32x4 av0[4], av1[4];
#pragma unroll
    for (int k = 0; k < 4; ++k) {
      const int row = (tid >> 5) + k * 8;
      const int col = (tid & 31) * 8;
      int gr = gr0i + row;
      gr = gr < 0 ? 0 : (gr > rowsMax ? rowsMax : gr);
      const float* p = xs + (((unsigned)gr << 8) + (unsigned)col);
      av0[k] = *(const f32x4*)p;
      av1[k] = *(const f32x4*)(p + 4);
    }
#pragma unroll
    for (int k = 0; k < 4; ++k) {
      const int o = tid + k * 256;          // flat octet = row*32 + oct
      const int row = o >> 5, oct = o & 31;
      *(bf16x8*)&aL[row][oct ^ (row & 7)][0] = pack8(av0[k], av1[k]);
    }
  }
  __syncthreads();

  f32x4 accz[2][4] = {};
  f32x4 acch[2][4] = {};

#pragma unroll
  for (int kk = 0; kk < 8; ++kk) {                       // K=32 per step
    bf16x8 af[2];
#pragma unroll
    for (int m = 0; m < 2; ++m) {
      const int row = m * 16 + l15;
      af[m] = *(const bf16x8*)&aL[row][(kk * 4 + l4) ^ (row & 7)][0];
    }
    const int cq = kk * 4 + l4;
    bf16x8 zf[4], hf[4];
#pragma unroll
    for (int n = 0; n < 4; ++n) {
      const int r = wn + n * 16 + l15;
      zf[n] = *(const bf16x8*)(wz_t + (cq * 256 + r) * 8);
      hf[n] = *(const bf16x8*)(wh_t + (cq * 256 + r) * 8);
    }
#pragma unroll
    for (int m = 0; m < 2; ++m)
#pragma unroll
      for (int n = 0; n < 4; ++n) {
        accz[m][n] = __builtin_amdgcn_mfma_f32_16x16x32_bf16(af[m], zf[n], accz[m][n], 0, 0, 0);
        acch[m][n] = __builtin_amdgcn_mfma_f32_16x16x32_bf16(af[m], hf[n], acch[m][n], 0, 0, 0);
      }
  }

  // ---- epilogue: (a,b), identity override, l0 write (32-bit offsets), reduce
  // sigmoid via v_rcp_f32 (__builtin_amdgcn_rcpf): 1 inst vs ~12 for the
  // full-precision division (no fast-math); ~1e-7 rel err, invisible in bf16.
  const unsigned base0 = ((unsigned)(32 * cb) << 8) + (unsigned)(wn + l15) + ((unsigned)l4 << 10);
#pragma unroll
  for (int n = 0; n < 4; ++n) {
    const int col = wn + n * 16 + l15;
    const float bzv = bz[col], bhv = bh[col];
#pragma unroll
    for (int m = 0; m < 2; ++m)
#pragma unroll
      for (int j = 0; j < 4; ++j) {
        const int e = m * 16 + l4 * 4 + j;               // slot within chunk
        const float zv = __builtin_amdgcn_rcpf(1.0f + __expf(-(accz[m][n][j] + bzv)));
        const float hv = acch[m][n][j] + bhv;
        float a = 1.0f - zv, b = zv * hv;
        if (cb == 0 && e == 0) { a = 1.0f; b = 0.0f; }   // prepended identity
        const unsigned u = cvtpk(a, b);
        if (cb < 512 || e == 0)
          l0b[base0 + (unsigned)(n * 16 + m * 4096 + j * 256)] = u;
        float ar, br; unpk(u, ar, br);
        accz[m][n][j] = ar; acch[m][n][j] = br;
      }
  }

  if (cb < 512) {
    const bool f3 = (l4 & 1) == 0;
    const bool f4 = (l4 & 2) == 0;
#pragma unroll
    for (int n = 0; n < 4; ++n) {
      float a4v[2], b4v[2];
#pragma unroll
      for (int m = 0; m < 2; ++m) {
        const float a10 = accz[m][n][0] * acch[m][n][0];
        const float b10 = acch[m][n][0] * accz[m][n][1] + acch[m][n][1];
        const float a11 = accz[m][n][2] * acch[m][n][2];
        const float b11 = acch[m][n][2] * accz[m][n][3] + acch[m][n][3];
        const float a2 = a10 * b10;
        const float b2 = b10 * a11 + b11;
        const float pa = __shfl_xor(a2, 16);
        const float pb = __shfl_xor(b2, 16);
        const float a3 = f3 ? a2 * b2 : pa * pb;
        const float b3 = f3 ? b2 * pa + pb : pb * a2 + b2;
        const float qa = __shfl_xor(a3, 32);
        const float qb = __shfl_xor(b3, 32);
        a4v[m] = f4 ? a3 * b3 : qa * qb;
        b4v[m] = f4 ? b3 * qa + qb : qb * a3 + b3;
      }
      const float a5 = a4v[0] * b4v[0];
      const float b5 = b4v[0] * a4v[1] + b4v[1];
      if (l4 == 0)
        l5b[((unsigned)cb << 8) + (unsigned)(wn + n * 16 + l15)] = f32x2{a5, b5};
    }
  }
}

// ---------------------------------------------------------------- chunk up-sweep f32 (L5 -> L10), 128 blocks
__global__ __launch_bounds__(256)
void chunk_up(const f32x2* __restrict__ src, f32x2* __restrict__ dst, int nCh, int nSrc)
{
  int idx = blockIdx.x * 256 + threadIdx.x;
  int total = Bsz * nCh * 256;
  if (idx >= total) return;
  int h = idx & 255, r = idx >> 8;
  int c = r % nCh, batch = r / nCh;
  size_t base = ((size_t)batch * nSrc + (size_t)c * 32) * 256 + h;

  float a1[16], b1[16];
#pragma unroll
  for (int i = 0; i < 16; ++i) {
    f32x2 e0 = src[base + (size_t)(2 * i) * 256];
    f32x2 e1 = src[base + (size_t)(2 * i + 1) * 256];
    a1[i] = e0[0] * e0[1];
    b1[i] = e0[1] * e1[0] + e1[1];
  }
#pragma unroll
  for (int n = 8; n >= 1; n >>= 1) {
#pragma unroll
    for (int i = 0; i < n; ++i) {
      float na = a1[2 * i] * b1[2 * i];
      float nb = b1[2 * i] * a1[2 * i + 1] + b1[2 * i + 1];
      a1[i] = na; b1[i] = nb;
    }
  }
  dst[((size_t)batch * nCh + c) * 256 + h] = f32x2{a1[0], b1[0]};
}

// ---------------------------------------------------------------- 16-element full tree scan (top levels), exact b-scan
__global__ void tree16(const f32x2* __restrict__ src, float* __restrict__ outB)
{
  int idx = blockIdx.x * 256 + threadIdx.x;
  if (idx >= Bsz * 256) return;
  int h = idx & 255, batch = idx >> 8;
  size_t base = (size_t)batch * 16 * 256 + h;

  float a0[16], b0[16];
#pragma unroll
  for (int i = 0; i < 16; ++i) { f32x2 e = src[base + (size_t)i * 256]; a0[i] = e[0]; b0[i] = e[1]; }
  float a1[8], b1[8];
#pragma unroll
  for (int i = 0; i < 8; ++i) { a1[i] = a0[2*i]*b0[2*i]; b1[i] = b0[2*i]*a0[2*i+1] + b0[2*i+1]; }
  float a2[4], b2[4];
#pragma unroll
  for (int i = 0; i < 4; ++i) { a2[i] = a1[2*i]*b1[2*i]; b2[i] = b1[2*i]*a1[2*i+1] + b1[2*i+1]; }
  float a3[2], b3[2];
#pragma unroll
  for (int i = 0; i < 2; ++i) { a3[i] = a2[2*i]*b2[2*i]; b3[i] = b2[2*i]*a2[2*i+1] + b2[2*i+1]; }
  float s3[2];
  s3[0] = b3[0];
  s3[1] = b3[0] * a3[1] + b3[1];
  float s2[4];
  s2[0] = b2[0]; s2[1] = s3[0]; s2[2] = s3[0] * a2[2] + b2[2]; s2[3] = s3[1];
  float s1[8];
  s1[0] = b1[0];
#pragma unroll
  for (int j = 0; j < 4; ++j) s1[2*j+1] = s2[j];
#pragma unroll
  for (int j = 1; j < 4; ++j) s1[2*j] = s2[j-1] * a1[2*j] + b1[2*j];
  float s0[16];
  s0[0] = b0[0];
#pragma unroll
  for (int j = 0; j < 8; ++j) s0[2*j+1] = s1[j];
#pragma unroll
  for (int j = 1; j < 8; ++j) s0[2*j] = s1[j-1] * a0[2*j] + b0[2*j];
#pragma unroll
  for (int i = 0; i < 16; ++i) outB[base + (size_t)i * 256] = s0[i];
}

// ---------------------------------------------------------------- chunk down-sweep f32 (L5 level): needs P=snext[c-1], S=snext[c]
__global__ __launch_bounds__(256, 2)
void chunk_down_f32(const f32x2* __restrict__ src, const float* __restrict__ snext,
                    float* __restrict__ outF, int nCh, int nFull, int nSrc)
{
  int idx = blockIdx.x * 256 + threadIdx.x;
  int total = Bsz * nCh * 256;
  if (idx >= total) return;
  int h = idx & 255, r = idx >> 8;
  int c = r % nCh, batch = r / nCh;
  size_t base = ((size_t)batch * nSrc + (size_t)c * 32) * 256 + h;
  bool hasP = (c > 0);
  float P = hasP ? snext[((size_t)batch * nFull + (c - 1)) * 256 + h] : 0.0f;
  float S = snext[((size_t)batch * nFull + c) * 256 + h];

  float ae[16], be[16], a1[16], b1[16];
#pragma unroll
  for (int i = 0; i < 16; ++i) {
    f32x2 e0 = src[base + (size_t)(2 * i) * 256];
    f32x2 e1 = src[base + (size_t)(2 * i + 1) * 256];
    ae[i] = e0[0]; be[i] = e0[1];
    a1[i] = e0[0] * e0[1];
    b1[i] = e0[1] * e1[0] + e1[1];
  }
  float a2[8], b2[8];
#pragma unroll
  for (int i = 0; i < 8; ++i) { a2[i] = a1[2*i]*b1[2*i]; b2[i] = b1[2*i]*a1[2*i+1] + b1[2*i+1]; }
  float a3[4], b3[4];
#pragma unroll
  for (int i = 0; i < 4; ++i) { a3[i] = a2[2*i]*b2[2*i]; b3[i] = b2[2*i]*a2[2*i+1] + b2[2*i+1]; }
  float a4[2], b4[2];
#pragma unroll
  for (int i = 0; i < 2; ++i) { a4[i] = a3[2*i]*b3[2*i]; b4[i] = b3[2*i]*a3[2*i+1] + b3[2*i+1]; }

  float s4[2];
  s4[0] = hasP ? P * a4[0] + b4[0] : b4[0];
  s4[1] = S;
  float s3[4];
  s3[0] = hasP ? P * a3[0] + b3[0] : b3[0];
  s3[1] = s4[0]; s3[2] = s4[0] * a3[2] + b3[2]; s3[3] = s4[1];
  float s2[8];
  s2[0] = hasP ? P * a2[0] + b2[0] : b2[0];
#pragma unroll
  for (int j = 0; j < 4; ++j) s2[2*j+1] = s3[j];
#pragma unroll
  for (int j = 1; j < 4; ++j) s2[2*j] = s3[j-1] * a2[2*j] + b2[2*j];
  float s1[16];
  s1[0] = hasP ? P * a1[0] + b1[0] : b1[0];
#pragma unroll
  for (int j = 0; j < 8; ++j) s1[2*j+1] = s2[j];
#pragma unroll
  for (int j = 1; j < 8; ++j) s1[2*j] = s2[j-1] * a1[2*j] + b1[2*j];

  outF[base] = hasP ? P * ae[0] + be[0] : be[0];
#pragma unroll
  for (int j = 0; j < 16; ++j) outF[base + (size_t)(2*j+1) * 256] = s1[j];
#pragma unroll
  for (int j = 1; j < 16; ++j) outF[base + (size_t)(2*j) * 256] = s1[j-1] * ae[j] + be[j];
}

// ---------------------------------------------------------------- fused L0 down-sweep + output projection (32-bit addressing)
// (256,3): cap 170 >= peak need (~120 scan-phase arch; ~80 arch + 32 acc
// projection) -> 3 blocks/CU for the latency-chain scan loads (was 2).
__global__ __launch_bounds__(256, 3)
void down_proj(const unsigned* __restrict__ l0, const float* __restrict__ s5b,
               const unsigned short* __restrict__ wo_t, const float* __restrict__ bo,
               float* __restrict__ out)
{
  __shared__ unsigned short pL[32 * 256];   // [row][h], h XOR-swizzled by ((row&7)<<3)

  const int tid = threadIdx.x;
  const int bc = blockIdx.x;
  const int c = bc % 513;
  const int batch = bc / 513;

  const unsigned* const l0b = l0 + (size_t)batch * (NL0 * 256);
  const float* const s5bb = s5b + (size_t)batch * (512 * 256);
  float* const outb = out + (size_t)batch * (Tsz * 256);

  {  // ---- scan phase: thread = h
    const int h = tid;
    const unsigned base = ((unsigned)(c * 32) << 8) + (unsigned)h;
    const bool hasP = (c > 0);
    const float P = hasP ? s5bb[((unsigned)(c - 1) << 8) + h] : 0.0f;

    if (c == 512) {                          // single tail element (t = 16383)
      float a0, b0; unpk(l0b[base], a0, b0);
      pL[h] = (unsigned short)f2bf(P * a0 + b0);
#pragma unroll
      for (int i = 1; i < 32; ++i)
        pL[i * 256 + (h ^ ((i & 7) << 3))] = 0;
    } else {
      const float S = s5bb[((unsigned)c << 8) + h];
      float ae[16], be[16], a1[16], b1[16];
#pragma unroll
      for (int i = 0; i < 16; ++i) {
        unsigned u0 = l0b[base + ((unsigned)(2 * i) << 8)];
        unsigned u1 = l0b[base + ((unsigned)(2 * i + 1) << 8)];
        float a0, b0, a1e, b1e;
        unpk(u0, a0, b0); unpk(u1, a1e, b1e);
        ae[i] = a0; be[i] = b0;
        a1[i] = a0 * b0; b1[i] = b0 * a1e + b1e;
      }
      float a2[8], b2[8];
#pragma unroll
      for (int i = 0; i < 8; ++i) { a2[i] = a1[2*i]*b1[2*i]; b2[i] = b1[2*i]*a1[2*i+1] + b1[2*i+1]; }
      float a3[4], b3[4];
#pragma unroll
      for (int i = 0; i < 4; ++i) { a3[i] = a2[2*i]*b2[2*i]; b3[i] = b2[2*i]*a2[2*i+1] + b2[2*i+1]; }
      float a4[2], b4[2];
#pragma unroll
      for (int i = 0; i < 2; ++i) { a4[i] = a3[2*i]*b3[2*i]; b4[i] = b3[2*i]*a3[2*i+1] + b3[2*i+1]; }

      float s4[2];
      s4[0] = hasP ? P * a4[0] + b4[0] : b4[0];
      s4[1] = S;
      float s3[4];
      s3[0] = hasP ? P * a3[0] + b3[0] : b3[0];
      s3[1] = s4[0]; s3[2] = s4[0] * a3[2] + b3[2]; s3[3] = s4[1];
      float s2[8];
      s2[0] = hasP ? P * a2[0] + b2[0] : b2[0];
#pragma unroll
      for (int j = 0; j < 4; ++j) s2[2*j+1] = s3[j];
#pragma unroll
      for (int j = 1; j < 4; ++j) s2[2*j] = s3[j-1] * a2[2*j] + b2[2*j];
      float s1[16];
      s1[0] = hasP ? P * a1[0] + b1[0] : b1[0];
#pragma unroll
      for (int j = 0; j < 8; ++j) s1[2*j+1] = s2[j];
#pragma unroll
      for (int j = 1; j < 8; ++j) s1[2*j] = s2[j-1] * a1[2*j] + b1[2*j];

      pL[h] = (unsigned short)f2bf(hasP ? P * ae[0] + be[0] : be[0]);
#pragma unroll
      for (int j = 0; j < 16; ++j) {
        const int row = 2 * j + 1;
        pL[row * 256 + (h ^ ((row & 7) << 3))] = (unsigned short)f2bf(s1[j]);
      }
#pragma unroll
      for (int j = 1; j < 16; ++j) {
        const int row = 2 * j;
        pL[row * 256 + (h ^ ((row & 7) << 3))] = (unsigned short)f2bf(s1[j-1] * ae[j] + be[j]);
      }
    }
  }
  __syncthreads();

  // ---- projection phase: M=32, N=64/wave, K=256; Wo frags from L2, pipelined
  const int wave = tid >> 6, lane = tid & 63, l15 = lane & 15, l4 = lane >> 4;
  const int wn = wave * 64;
  f32x4 acc[2][4] = {};
  bf16x8 wc[4], wnx[4];
#pragma unroll
  for (int n = 0; n < 4; ++n)
    wc[n] = *(const bf16x8*)(wo_t + (l4 * 256 + wn + n * 16 + l15) * 8);   // kk=0
#pragma unroll
  for (int kk = 0; kk < 8; ++kk) {
    if (kk < 7) {
#pragma unroll
      for (int n = 0; n < 4; ++n)
        wnx[n] = *(const bf16x8*)(wo_t + (((kk + 1) * 4 + l4) * 256 + wn + n * 16 + l15) * 8);
    }
    bf16x8 af[2];
#pragma unroll
    for (int m = 0; m < 2; ++m) {
      const int row = m * 16 + l15;
      af[m] = *(const bf16x8*)&pL[row * 256 + ((kk * 32 + l4 * 8) ^ ((row & 7) << 3))];
    }
#pragma unroll
    for (int m = 0; m < 2; ++m)
#pragma unroll
      for (int n = 0; n < 4; ++n)
        acc[m][n] = __builtin_amdgcn_mfma_f32_16x16x32_bf16(af[m], wc[n], acc[m][n], 0, 0, 0);
    if (kk < 7) {
      wc[0] = wnx[0]; wc[1] = wnx[1]; wc[2] = wnx[2]; wc[3] = wnx[3];
    }
  }

  const int tBase = 32 * c - 1;
#pragma unroll
  for (int n = 0; n < 4; ++n) {
    const int col = wn + n * 16 + l15;
    const float bv = bo[col];
#pragma unroll
    for (int m = 0; m < 2; ++m)
#pragma unroll
      for (int j = 0; j < 4; ++j) {
        const int t = tBase + m * 16 + l4 * 4 + j;
        if ((unsigned)t < (unsigned)Tsz)
          outb[((unsigned)t << 8) + (unsigned)col] = acc[m][n][j] + bv;
      }
  }
}

// ================================================================ host
extern "C" void kernel_launch(void* const* d_in, const int* in_sizes, int n_in,
                              void* d_out, int out_size, void* d_ws, size_t ws_size,
                              hipStream_t stream)
{
  (void)in_sizes; (void)n_in;
  const float* xs = (const float*)d_in[0];
  const float* Wz = (const float*)d_in[1];
  const float* bz = (const float*)d_in[2];
  const float* Wh = (const float*)d_in[3];
  const float* bh = (const float*)d_in[4];
  const float* Wo = (const float*)d_in[5];
  const float* bo = (const float*)d_in[6];
  float* out = (float*)d_out;

  const size_t n_l0  = (size_t)Bsz * NL0 * 256;
  const size_t n_l5  = (size_t)Bsz * NL5 * 256;
  const size_t n_l10 = (size_t)Bsz * NL10 * 256;

  unsigned* l0    = (unsigned*)d_ws;
  f32x2* l5ab     = (f32x2*)(l0 + n_l0);
  f32x2* l10ab    = l5ab + n_l5;
  float* s10b     = (float*)(l10ab + n_l10);
  float* s5b      = s10b + n_l10;
  unsigned short* wt = (unsigned short*)(s5b + n_l5);

  const size_t need = n_l0 * 4 + n_l5 * 8 + n_l10 * 8 + n_l10 * 4 + n_l5 * 4 + 3 * 65536 * 2;
  if (ws_size < need) {
    fill_sentinel<<<(out_size + 255) / 256, 256, 0, stream>>>(out, out_size);
    return;
  }

  prep_weights<<<96, 256, 0, stream>>>(Wz, Wh, Wo, wt);
  gemm_zh<<<Bsz * 513, 256, 0, stream>>>(xs, wt, bz, bh, l0, l5ab);
  chunk_up<<<(Bsz * 16 * 256) / 256, 256, 0, stream>>>(l5ab, l10ab, 16, NL5);
  tree16<<<8, 256, 0, stream>>>(l10ab, s10b);
  chunk_down_f32<<<(Bsz * 16 * 256) / 256, 256, 0, stream>>>(l5ab, s10b, s5b, 16, 16, NL5);
  down_proj<<<Bsz * 513, 256, 0, stream>>>(l0, s5b, wt + 2 * 65536, bo, out);
}